// Round 1
// baseline (261.983 us; speedup 1.0000x reference)
//
#include <hip/hip_runtime.h>
#include <hip/hip_bf16.h>

// Problem constants (from reference setup_inputs)
#define B_ 64
#define C_ 256
#define T_ 2048
#define EPS_ 1e-4f
#define NPC ((float)(B_ * T_))   // elements per channel = 131072

// ---------------------------------------------------------------------------
// Kernel 0: zero the stats accumulators (ws is poisoned 0xAA before each call)
// ---------------------------------------------------------------------------
__global__ __launch_bounds__(512) void bntt_init(float* stats) {
    int i = threadIdx.x;               // 512 threads cover 2*C_ floats
    if (i < 2 * C_) stats[i] = 0.0f;
}

// ---------------------------------------------------------------------------
// Kernel 1: per-channel sum & sumsq. Grid = C_ * SPLITS blocks of 256.
// Each block reduces (B_/SPLITS) batch rows of one channel, float4 coalesced.
// ---------------------------------------------------------------------------
#define SPLITS 8
#define BPB (B_ / SPLITS)   // 8 batches per block

__global__ __launch_bounds__(256) void bntt_stats(const float* __restrict__ x,
                                                  float* __restrict__ stats) {
    const int c  = blockIdx.x & (C_ - 1);
    const int s  = blockIdx.x >> 8;          // split index
    const int tid = threadIdx.x;

    float sum = 0.0f, sumsq = 0.0f;
    const int b0 = s * BPB;
    for (int b = b0; b < b0 + BPB; ++b) {
        const float4* p = (const float4*)(x + (size_t)b * (C_ * T_) + (size_t)c * T_);
        #pragma unroll
        for (int i = tid; i < T_ / 4; i += 256) {
            float4 v = p[i];
            sum   += v.x + v.y + v.z + v.w;
            sumsq += v.x * v.x + v.y * v.y + v.z * v.z + v.w * v.w;
        }
    }
    // wave (64-lane) shuffle reduction
    #pragma unroll
    for (int off = 32; off > 0; off >>= 1) {
        sum   += __shfl_down(sum, off);
        sumsq += __shfl_down(sumsq, off);
    }
    __shared__ float ls[4], lss[4];
    const int wave = tid >> 6, lane = tid & 63;
    if (lane == 0) { ls[wave] = sum; lss[wave] = sumsq; }
    __syncthreads();
    if (tid == 0) {
        float S  = ls[0] + ls[1] + ls[2] + ls[3];
        float SS = lss[0] + lss[1] + lss[2] + lss[3];
        atomicAdd(&stats[c], S);
        atomicAdd(&stats[C_ + c], SS);
    }
}

// ---------------------------------------------------------------------------
// Kernel 2: finalize — stats[c] := mean, stats[C_+c] := inv_std  (in place)
// ---------------------------------------------------------------------------
__global__ __launch_bounds__(256) void bntt_finalize(float* stats) {
    int c = threadIdx.x;   // one block of 256
    float mean = stats[c] / NPC;
    float var  = stats[C_ + c] / NPC - mean * mean;
    stats[c]       = mean;
    stats[C_ + c]  = rsqrtf(var + EPS_);
}

// ---------------------------------------------------------------------------
// Kernel 3 (fast path): fused transpose+prep.
// gamma,beta are [T_,C_]; produce scale,shift as [C_,T_]:
//   scale[c][t] = gamma[t][c] * istd[c]
//   shift[c][t] = beta[t][c]  - mean[c] * scale[c][t]
// Tiled 32x32 through LDS for coalesced read AND write.
// ---------------------------------------------------------------------------
__global__ __launch_bounds__(1024) void bntt_prep(const float* __restrict__ gamma,
                                                  const float* __restrict__ beta,
                                                  const float* __restrict__ stats,
                                                  float* __restrict__ scale,
                                                  float* __restrict__ shift) {
    __shared__ float tg[32][33];
    __shared__ float tb[32][33];
    const int tx = threadIdx.x & 31;
    const int ty = threadIdx.x >> 5;
    const int c0 = blockIdx.x * 32;          // gridDim.x = C_/32 = 8
    const int t0 = blockIdx.y * 32;          // gridDim.y = T_/32 = 64

    // coalesced read: consecutive tx -> consecutive c
    tg[ty][tx] = gamma[(size_t)(t0 + ty) * C_ + (c0 + tx)];
    tb[ty][tx] = beta [(size_t)(t0 + ty) * C_ + (c0 + tx)];
    __syncthreads();

    // coalesced write: consecutive tx -> consecutive t
    const int c = c0 + ty;
    const float mean = stats[c];
    const float istd = stats[C_ + c];
    const float g = tg[tx][ty];
    const float bb = tb[tx][ty];
    const float sc = g * istd;
    scale[(size_t)c * T_ + (t0 + tx)] = sc;
    shift[(size_t)c * T_ + (t0 + tx)] = fmaf(-mean, sc, bb);
}

// ---------------------------------------------------------------------------
// Kernel 4 (fast path): normalize. One float4 per thread, fully coalesced.
// ---------------------------------------------------------------------------
__global__ __launch_bounds__(256) void bntt_norm(const float* __restrict__ x,
                                                 const float* __restrict__ scale,
                                                 const float* __restrict__ shift,
                                                 float* __restrict__ out) {
    const int idx4 = blockIdx.x * 256 + threadIdx.x;   // vec4 index
    const int t4   = idx4 & (T_ / 4 - 1);              // vec4 index within row
    const int row  = idx4 >> 9;                        // (b*C_ + c)
    const int c    = row & (C_ - 1);

    const float4 xv = ((const float4*)x)[idx4];
    const float4 sc = ((const float4*)(scale + (size_t)c * T_))[t4];
    const float4 sh = ((const float4*)(shift + (size_t)c * T_))[t4];
    float4 o;
    o.x = fmaf(xv.x, sc.x, sh.x);
    o.y = fmaf(xv.y, sc.y, sh.y);
    o.z = fmaf(xv.z, sc.z, sh.z);
    o.w = fmaf(xv.w, sc.w, sh.w);
    ((float4*)out)[idx4] = o;
}

// ---------------------------------------------------------------------------
// Kernel 4b (fallback, ws too small for scale/shift): read gamma/beta [T,C]
// directly (strided but L2/L3-hot: only 4 MiB reused 64x).
// ---------------------------------------------------------------------------
__global__ __launch_bounds__(256) void bntt_norm_fb(const float* __restrict__ x,
                                                    const float* __restrict__ gamma,
                                                    const float* __restrict__ beta,
                                                    const float* __restrict__ stats,
                                                    float* __restrict__ out) {
    const int idx4 = blockIdx.x * 256 + threadIdx.x;
    const int t4   = idx4 & (T_ / 4 - 1);
    const int row  = idx4 >> 9;
    const int c    = row & (C_ - 1);
    const int t    = t4 * 4;

    const float mean = stats[c];
    const float istd = stats[C_ + c];
    const float4 xv = ((const float4*)x)[idx4];
    float4 o;
    #pragma unroll
    for (int j = 0; j < 4; ++j) {
        float g  = gamma[(size_t)(t + j) * C_ + c];
        float bb = beta [(size_t)(t + j) * C_ + c];
        float sc = g * istd;
        float sh = fmaf(-mean, sc, bb);
        float xs = (&xv.x)[j];
        (&o.x)[j] = fmaf(xs, sc, sh);
    }
    ((float4*)out)[idx4] = o;
}

extern "C" void kernel_launch(void* const* d_in, const int* in_sizes, int n_in,
                              void* d_out, int out_size, void* d_ws, size_t ws_size,
                              hipStream_t stream) {
    const float* x     = (const float*)d_in[0];
    const float* gamma = (const float*)d_in[1];
    const float* beta  = (const float*)d_in[2];
    float* out = (float*)d_out;

    float* stats = (float*)d_ws;                       // 2*C_ floats
    float* scale = stats + 2 * C_;                     // C_*T_ floats
    float* shift = scale + (size_t)C_ * T_;            // C_*T_ floats
    const size_t need = (2 * C_ + 2 * (size_t)C_ * T_) * sizeof(float);

    bntt_init<<<1, 512, 0, stream>>>(stats);
    bntt_stats<<<C_ * SPLITS, 256, 0, stream>>>(x, stats);
    bntt_finalize<<<1, 256, 0, stream>>>(stats);

    const int nvec = B_ * C_ * T_ / 4;                 // 8388608
    if (ws_size >= need) {
        dim3 pg(C_ / 32, T_ / 32);
        bntt_prep<<<pg, 1024, 0, stream>>>(gamma, beta, stats, scale, shift);
        bntt_norm<<<nvec / 256, 256, 0, stream>>>(x, scale, shift, out);
    } else {
        bntt_norm_fb<<<nvec / 256, 256, 0, stream>>>(x, gamma, beta, stats, out);
    }
}

// Round 2
// 252.268 us; speedup vs baseline: 1.0385x; 1.0385x over previous
//
#include <hip/hip_runtime.h>
#include <hip/hip_bf16.h>

// Problem constants (from reference setup_inputs)
#define B_ 64
#define C_ 256
#define T_ 2048
#define EPS_ 1e-4f
#define NPC ((float)(B_ * T_))   // elements per channel = 131072

#define SPLITS 8
#define BPB (B_ / SPLITS)        // 8 batch rows per stats block
#define T4 (T_ / 4)              // 512 vec4 per row

typedef float f4 __attribute__((ext_vector_type(4)));

// ---------------------------------------------------------------------------
// Kernel 1: per-channel partial sum & sumsq. Grid = C_*SPLITS = 2048 blocks
// of 256 (8 blocks/CU -> 32 waves/CU). No atomics, no init: block (c,s)
// writes partials to a disjoint slot.
//   psum  = ws[0 .. 2047]        layout [s][c]
//   psq   = ws[2048 .. 4095]
// ---------------------------------------------------------------------------
__global__ __launch_bounds__(256) void bntt_stats(const float* __restrict__ x,
                                                  float* __restrict__ partials) {
    const int c   = blockIdx.x & (C_ - 1);
    const int s   = blockIdx.x >> 8;
    const int tid = threadIdx.x;

    float sum = 0.0f, sumsq = 0.0f;
    const int b0 = s * BPB;
    #pragma unroll
    for (int b = 0; b < BPB; ++b) {
        const f4* p = (const f4*)(x + (size_t)(b0 + b) * (C_ * T_) + (size_t)c * T_);
        #pragma unroll
        for (int i = 0; i < T4 / 256; ++i) {
            f4 v = p[tid + i * 256];
            sum   += v.x + v.y + v.z + v.w;
            sumsq += v.x * v.x + v.y * v.y + v.z * v.z + v.w * v.w;
        }
    }
    #pragma unroll
    for (int off = 32; off > 0; off >>= 1) {
        sum   += __shfl_down(sum, off);
        sumsq += __shfl_down(sumsq, off);
    }
    __shared__ float ls[4], lss[4];
    const int wave = tid >> 6, lane = tid & 63;
    if (lane == 0) { ls[wave] = sum; lss[wave] = sumsq; }
    __syncthreads();
    if (tid == 0) {
        partials[s * C_ + c]                   = ls[0] + ls[1] + ls[2] + ls[3];
        partials[SPLITS * C_ + s * C_ + c]     = lss[0] + lss[1] + lss[2] + lss[3];
    }
}

// ---------------------------------------------------------------------------
// Kernel 2: finalize + transpose prep fused.
// gamma,beta are [T_,C_]; produce scale,shift as [C_,T_]:
//   scale[c][t] = gamma[t][c] * istd[c]
//   shift[c][t] = beta[t][c]  - mean[c] * scale[c][t]
// 32x32 LDS tile transpose; mean/istd computed from partials by 32 threads.
// ---------------------------------------------------------------------------
__global__ __launch_bounds__(1024) void bntt_prep(const float* __restrict__ gamma,
                                                  const float* __restrict__ beta,
                                                  const float* __restrict__ partials,
                                                  float* __restrict__ scale,
                                                  float* __restrict__ shift) {
    __shared__ float tg[32][33];
    __shared__ float tb[32][33];
    __shared__ float smean[32], sistd[32];
    const int tx = threadIdx.x & 31;
    const int ty = threadIdx.x >> 5;
    const int c0 = blockIdx.x * 32;          // gridDim.x = C_/32 = 8
    const int t0 = blockIdx.y * 32;          // gridDim.y = T_/32 = 64

    if (threadIdx.x < 32) {
        const int c = c0 + threadIdx.x;
        float S = 0.0f, SS = 0.0f;
        #pragma unroll
        for (int s = 0; s < SPLITS; ++s) {
            S  += partials[s * C_ + c];
            SS += partials[SPLITS * C_ + s * C_ + c];
        }
        float mean = S / NPC;
        float var  = SS / NPC - mean * mean;
        smean[threadIdx.x] = mean;
        sistd[threadIdx.x] = rsqrtf(var + EPS_);
    }
    // coalesced read: consecutive tx -> consecutive c
    tg[ty][tx] = gamma[(size_t)(t0 + ty) * C_ + (c0 + tx)];
    tb[ty][tx] = beta [(size_t)(t0 + ty) * C_ + (c0 + tx)];
    __syncthreads();

    // coalesced write: consecutive tx -> consecutive t; channel = c0+ty
    const float mean = smean[ty];
    const float istd = sistd[ty];
    const float sc = tg[tx][ty] * istd;
    scale[(size_t)(c0 + ty) * T_ + (t0 + tx)] = sc;
    shift[(size_t)(c0 + ty) * T_ + (t0 + tx)] = fmaf(-mean, sc, tb[tx][ty]);
}

// ---------------------------------------------------------------------------
// Kernel 3: normalize. Each thread owns one (c, t4) vec4: loads scale/shift
// ONCE into registers, then streams BCHUNK batch rows (coalesced along t).
// Non-temporal stores keep x resident in L2/L3.
// Grid = 1024 blocks x 256: blockIdx low 9 bits -> (c,t4) group, bit 9 -> b half.
// ---------------------------------------------------------------------------
#define BCHUNK 32
__global__ __launch_bounds__(256) void bntt_norm(const float* __restrict__ x,
                                                 const float* __restrict__ scale,
                                                 const float* __restrict__ shift,
                                                 float* __restrict__ out) {
    const int p   = (blockIdx.x & 511) * 256 + threadIdx.x;  // (c,t4) index
    const int c   = p >> 9;                                  // 512 vec4 per row
    const int t4  = p & (T4 - 1);
    const int b0  = (blockIdx.x >> 9) * BCHUNK;

    const f4 sc = ((const f4*)scale)[(size_t)c * T4 + t4];
    const f4 sh = ((const f4*)shift)[(size_t)c * T4 + t4];

    size_t idx = (size_t)(b0 * C_ + c) * T4 + t4;
    const size_t step = (size_t)C_ * T4;                     // one batch row
    #pragma unroll 4
    for (int b = 0; b < BCHUNK; ++b) {
        f4 xv = ((const f4*)x)[idx];
        f4 o;
        o.x = fmaf(xv.x, sc.x, sh.x);
        o.y = fmaf(xv.y, sc.y, sh.y);
        o.z = fmaf(xv.z, sc.z, sh.z);
        o.w = fmaf(xv.w, sc.w, sh.w);
        __builtin_nontemporal_store(o, &((f4*)out)[idx]);
        idx += step;
    }
}

// ---------------------------------------------------------------------------
// Fallback normalize (ws too small for scale/shift): read gamma/beta [T,C]
// directly; each thread still reuses its affine over BCHUNK batches.
// ---------------------------------------------------------------------------
__global__ __launch_bounds__(256) void bntt_norm_fb(const float* __restrict__ x,
                                                    const float* __restrict__ gamma,
                                                    const float* __restrict__ beta,
                                                    const float* __restrict__ partials,
                                                    float* __restrict__ out) {
    const int p   = (blockIdx.x & 511) * 256 + threadIdx.x;
    const int c   = p >> 9;
    const int t4  = p & (T4 - 1);
    const int t   = t4 * 4;
    const int b0  = (blockIdx.x >> 9) * BCHUNK;

    float S = 0.0f, SS = 0.0f;
    #pragma unroll
    for (int s = 0; s < SPLITS; ++s) {
        S  += partials[s * C_ + c];
        SS += partials[SPLITS * C_ + s * C_ + c];
    }
    const float mean = S / NPC;
    const float istd = rsqrtf(SS / NPC - mean * mean + EPS_);

    f4 sc, sh;
    #pragma unroll
    for (int j = 0; j < 4; ++j) {
        float g  = gamma[(size_t)(t + j) * C_ + c];
        float bb = beta [(size_t)(t + j) * C_ + c];
        float s1 = g * istd;
        ((float*)&sc)[j] = s1;
        ((float*)&sh)[j] = fmaf(-mean, s1, bb);
    }
    size_t idx = (size_t)(b0 * C_ + c) * T4 + t4;
    const size_t step = (size_t)C_ * T4;
    #pragma unroll 4
    for (int b = 0; b < BCHUNK; ++b) {
        f4 xv = ((const f4*)x)[idx];
        f4 o;
        o.x = fmaf(xv.x, sc.x, sh.x);
        o.y = fmaf(xv.y, sc.y, sh.y);
        o.z = fmaf(xv.z, sc.z, sh.z);
        o.w = fmaf(xv.w, sc.w, sh.w);
        __builtin_nontemporal_store(o, &((f4*)out)[idx]);
        idx += step;
    }
}

extern "C" void kernel_launch(void* const* d_in, const int* in_sizes, int n_in,
                              void* d_out, int out_size, void* d_ws, size_t ws_size,
                              hipStream_t stream) {
    const float* x     = (const float*)d_in[0];
    const float* gamma = (const float*)d_in[1];
    const float* beta  = (const float*)d_in[2];
    float* out = (float*)d_out;

    float* partials = (float*)d_ws;                     // 2*SPLITS*C_ = 4096 floats
    float* scale    = partials + 2 * SPLITS * C_;       // C_*T_ floats
    float* shift    = scale + (size_t)C_ * T_;          // C_*T_ floats
    const size_t need = (2 * SPLITS * C_ + 2 * (size_t)C_ * T_) * sizeof(float);

    bntt_stats<<<C_ * SPLITS, 256, 0, stream>>>(x, partials);

    const int ngrid = (C_ * T4 / 256) * (B_ / BCHUNK);  // 512 * 2 = 1024 blocks
    if (ws_size >= need) {
        dim3 pg(C_ / 32, T_ / 32);
        bntt_prep<<<pg, 1024, 0, stream>>>(gamma, beta, partials, scale, shift);
        bntt_norm<<<ngrid, 256, 0, stream>>>(x, scale, shift, out);
    } else {
        bntt_norm_fb<<<ngrid, 256, 0, stream>>>(x, gamma, beta, partials, out);
    }
}